// Round 12
// baseline (305.282 us; speedup 1.0000x reference)
//
#include <hip/hip_runtime.h>
#include <hip/hip_bf16.h>

#define NRES   768
#define C_S    256
#define C_P    128
#define FEAT   64
#define NTILES (NRES * (NRES / 64))   // 9216
#define NEDGE  (NRES * NRES)          // 589824

typedef float f32x4 __attribute__((ext_vector_type(4)));
typedef short s16x8 __attribute__((ext_vector_type(8)));
typedef short s16x4 __attribute__((ext_vector_type(4)));

__device__ __forceinline__ short to_bf16(float f) {
    unsigned u = __builtin_bit_cast(unsigned, f);
    u += 0x7fffu + ((u >> 16) & 1u);   // RNE
    return (short)(u >> 16);
}

// Streaming store: device-scope, L2 no-allocate (sc0 sc1 nt).
__device__ __forceinline__ void store_stream(float* p, f32x4 v) {
    asm volatile("global_store_dwordx4 %0, %1, off sc0 sc1 nt"
                 :: "v"(p), "v"(v) : "memory");
}

// ---------------------------------------------------------------------------
// R12 PROBE: known-good pure-write kernel (copy-style: grid-stride f32x4,
// 1KB contiguous per wave-instruction) over the whole output buffer. Measures
// achievable pure-write BW on this exact buffer as a separate rocprof
// dispatch. Edge kernel overwrites every element afterwards -> correct.
__global__ void probe_fill_kernel(float* __restrict__ p, size_t n4) {
    const size_t stride = (size_t)gridDim.x * blockDim.x;
    f32x4 z = {0.0f, 0.0f, 0.0f, 0.0f};
    for (size_t idx = (size_t)blockIdx.x * blockDim.x + threadIdx.x; idx < n4; idx += stride)
        ((f32x4*)p)[idx] = z;
}

// ---------------------------------------------------------------------------
__device__ __forceinline__ int bin_idx(float d) {
    const float lo0  = 0.001f;
    const float step = (20.0f - 0.001f) / 21.0f;
    int k = (int)floorf((d - lo0) / step);
    if (k < -1) k = -1;
    if (k > 21) k = 21;
    for (int kk = k + 1; kk >= k - 1; --kk) {
        if (kk < 0 || kk > 21) continue;
        float lk = lo0 + (float)kk * step;
        float uk = (kk < 21) ? (lo0 + (float)(kk + 1) * step) : 1e8f;
        if (d > lk && d < uk) return kk;
    }
    return -1;
}

// ---------------------------------------------------------------------------
__global__ void bins_kernel(const float* __restrict__ tp, const float* __restrict__ sp,
                            unsigned short* __restrict__ bins) {
    const int idx = blockIdx.x * 256 + threadIdx.x;
    if (idx >= NEDGE) return;
    const int i = idx / NRES;
    const int j = idx - i * NRES;
    float dx = tp[i*3+0] - tp[j*3+0];
    float dy = tp[i*3+1] - tp[j*3+1];
    float dz = tp[i*3+2] - tp[j*3+2];
    const int bd = bin_idx(sqrtf(dx*dx + dy*dy + dz*dz));
    dx = sp[i*3+0] - sp[j*3+0];
    dy = sp[i*3+1] - sp[j*3+1];
    dz = sp[i*3+2] - sp[j*3+2];
    const int bs = bin_idx(sqrtf(dx*dx + dy*dy + dz*dz));
    bins[idx] = (unsigned short)((bd + 1) | ((bs + 1) << 8));
}

// ---------------------------------------------------------------------------
__global__ void node_kernel(const float* __restrict__ s, const float* __restrict__ dm,
                            const float* __restrict__ W_sp, const float* __restrict__ b_sp,
                            const float* __restrict__ W1, const float* __restrict__ b1,
                            float* __restrict__ A, float* __restrict__ Bt) {
    __shared__ float srow[C_S];
    __shared__ float psh[FEAT];
    const int i = blockIdx.x;
    const int t = threadIdx.x;  // 128 threads
    srow[t]       = s[i * C_S + t];
    srow[t + 128] = s[i * C_S + 128 + t];
    __syncthreads();
    if (t < FEAT) {
        float acc = b_sp[t];
        for (int m = 0; m < C_S; ++m) acc = fmaf(srow[m], W_sp[m * FEAT + t], acc);
        psh[t] = acc;
    }
    __syncthreads();
    const float d = dm[i];
    float accA = fmaf(d, W1[236 * C_P + t], b1[t]);
    float accB = d * W1[237 * C_P + t];
    for (int k = 0; k < FEAT; ++k) {
        float p = psh[k];
        accA = fmaf(p, W1[k * C_P + t], accA);
        accB = fmaf(p, W1[(FEAT + k) * C_P + t], accB);
    }
    A[i * C_P + t]  = accA;
    Bt[i * C_P + t] = accB;
}

// ---------------------------------------------------------------------------
__global__ void wcomb_kernel(const float* __restrict__ W_rp, const float* __restrict__ b_rp,
                             const float* __restrict__ W1, float* __restrict__ Wcomb) {
    const int k = blockIdx.x;   // 0..64
    const int c = threadIdx.x;  // 128
    float acc = 0.0f;
    if (k < FEAT) {
        for (int m = 0; m < FEAT; ++m)
            acc = fmaf(W_rp[k * FEAT + m], W1[(2 * FEAT + m) * C_P + c], acc);
    } else {
        for (int m = 0; m < FEAT; ++m)
            acc = fmaf(b_rp[m], W1[(2 * FEAT + m) * C_P + c], acc);
    }
    Wcomb[k * C_P + c] = acc;
}

// ---------------------------------------------------------------------------
__global__ void rp_kernel(const float* __restrict__ Wcomb, float* __restrict__ RP) {
    __shared__ float emb[FEAT];
    const int bi = blockIdx.x;            // 0..1534
    const float d = (float)(bi - (NRES - 1));
    const int c = threadIdx.x;            // 128
    if (c < FEAT / 2) {
        float expo = 2.0f * (float)c / (float)FEAT;
        float freq = 3.14159265358979323846f / powf(2056.0f, expo);
        float ang = d * freq;
        emb[c]            = sinf(ang);
        emb[c + FEAT / 2] = cosf(ang);
    }
    __syncthreads();
    float acc = Wcomb[FEAT * C_P + c];
    for (int k = 0; k < FEAT; ++k) acc = fmaf(emb[k], Wcomb[k * C_P + c], acc);
    RP[bi * C_P + c] = acc;
}

// ---------------------------------------------------------------------------
__global__ void wt_kernel(const float* __restrict__ W2, const float* __restrict__ W3,
                          short* __restrict__ Wt2, short* __restrict__ Wt3) {
    const int n = blockIdx.x & 127;
    const int k = threadIdx.x;
    if (blockIdx.x < 128) Wt2[n * C_P + k] = to_bf16(W2[k * C_P + n]);
    else                  Wt3[n * C_P + k] = to_bf16(W3[k * C_P + n]);
}

// ---------------------------------------------------------------------------
// Edge kernel: UNCHANGED from R11 (best known: 247us, ~1.2 TB/s write).
__global__ __launch_bounds__(512, 4) void edge_kernel(
    const float* __restrict__ A, const float* __restrict__ Bt,
    const float* __restrict__ RP, const float* __restrict__ W1,
    const short* __restrict__ Wt2, const short* __restrict__ Wt3,
    const float* __restrict__ b2, const float* __restrict__ b3,
    const float* __restrict__ lng, const float* __restrict__ lnb,
    const unsigned short* __restrict__ bins,
    const float* __restrict__ pm, float* __restrict__ out)
{
    __shared__ short h1s[64 * C_P];   // bf16, XOR-swizzled rows
    __shared__ short h2s[64 * C_P];
    __shared__ float redS[64 * 4];    // [e][chan-wave] sum
    __shared__ float redQ[64 * 4];    // [e][chan-wave] sumsq

    const int t    = threadIdx.x;
    const int lane = t & 63;
    const int q    = t >> 6;       // wave 0..7
    const int m    = lane & 15;
    const int kg   = lane >> 4;
    const int wq   = q >> 2;       // edge half (0..1)
    const int cq   = q & 3;        // channel quarter
    const int c0   = cq * 32;
    const int c4   = t & 31;       // phase-1: 16B chunk
    const int er   = t >> 5;       // phase-1: row 0..15

    for (int tile = blockIdx.x; tile < NTILES; tile += gridDim.x) {
        const int i  = tile / 12;
        const int j0 = (tile % 12) * 64;

        // anti-LICM: opaque redefinition so weight/bias loads stay in-loop
        // (hoisting them under a tight reg cap => scratch spill, R4/R6-R8).
        const short* w2p = Wt2;
        const short* w3p = Wt3;
        const float* b2p = b2;
        const float* b3p = b3;
        const float* gp  = lng;
        const float* bp  = lnb;
        asm volatile("" : "+s"(w2p), "+s"(w3p), "+s"(b2p), "+s"(b3p), "+s"(gp), "+s"(bp));

        // ---- early issues: layer-2 weights + pm (hide under phase 1)
        s16x8 wf2[2][4];
#pragma unroll
        for (int nt = 0; nt < 2; ++nt) {
            const int n = c0 + nt * 16 + m;
#pragma unroll
            for (int ks = 0; ks < 4; ++ks)
                wf2[nt][ks] = *(const s16x8*)(w2p + n * C_P + ks * 32 + kg * 8);
        }
        float pmv[2];
#pragma unroll
        for (int et = 0; et < 2; ++et) pmv[et] = pm[i * NRES + j0 + wq * 32 + et * 16 + m];

        // ---------- phase 1 (coalesced): h1[e][c] = relu(A+B+RP+Wd+Ws) ----------
        {
            const f32x4 aCh = *(const f32x4*)(A + i * C_P + c4 * 4);
#pragma unroll
            for (int it = 0; it < 4; ++it) {
                const int e = it * 16 + er;
                const int j = j0 + e;
                const f32x4 b = *(const f32x4*)(Bt + j * C_P + c4 * 4);
                const f32x4 r = *(const f32x4*)(RP + (i - j + NRES - 1) * C_P + c4 * 4);
                const unsigned pk = bins[i * NRES + j];
                const int bd = (int)(pk & 0xffu) - 1;
                const int bs = (int)(pk >> 8) - 1;
                const f32x4 wd  = *(const f32x4*)(W1 + (192 + (bd < 0 ? 0 : bd)) * C_P + c4 * 4);
                const f32x4 wsb = *(const f32x4*)(W1 + (214 + (bs < 0 ? 0 : bs)) * C_P + c4 * 4);
                const float fd = (bd < 0) ? 0.0f : 1.0f;
                const float fs = (bs < 0) ? 0.0f : 1.0f;
                s16x4 pkv;
#pragma unroll
                for (int u = 0; u < 4; ++u)
                    pkv[u] = to_bf16(fmaxf(aCh[u] + b[u] + r[u] + fd * wd[u] + fs * wsb[u], 0.0f));
                const int byt = (e * 256 + c4 * 8) ^ ((e & 15) << 4);
                *(s16x4*)((char*)h1s + byt) = pkv;
            }
        }
        __syncthreads();   // B1: h1 ready

        // ---------- layer 2: h2' = relu(W2^T · h1^T + b2) via MFMA ----------
        f32x4 acc[2][2];
        {
            f32x4 b2f0 = *(const f32x4*)(b2p + c0 + kg * 4);
            f32x4 b2f1 = *(const f32x4*)(b2p + c0 + 16 + kg * 4);
#pragma unroll
            for (int et = 0; et < 2; ++et) { acc[0][et] = b2f0; acc[1][et] = b2f1; }
        }
#pragma unroll
        for (int ks = 0; ks < 4; ++ks) {
#pragma unroll
            for (int et = 0; et < 2; ++et) {
                const int e = wq * 32 + et * 16 + m;
                const int byt = (e * 256 + (ks * 32 + kg * 8) * 2) ^ (m << 4);
                s16x8 hf = *(const s16x8*)((const char*)h1s + byt);
                acc[0][et] = __builtin_amdgcn_mfma_f32_16x16x32_bf16(wf2[0][ks], hf, acc[0][et], 0, 0, 0);
                acc[1][et] = __builtin_amdgcn_mfma_f32_16x16x32_bf16(wf2[1][ks], hf, acc[1][et], 0, 0, 0);
            }
        }

        // ---- layer-3 weights (wf2 dead; hide under pack+B2)
        s16x8 wf3[2][4];
#pragma unroll
        for (int nt = 0; nt < 2; ++nt) {
            const int n = c0 + nt * 16 + m;
#pragma unroll
            for (int ks = 0; ks < 4; ++ks)
                wf3[nt][ks] = *(const s16x8*)(w3p + n * C_P + ks * 32 + kg * 8);
        }

#pragma unroll
        for (int nt = 0; nt < 2; ++nt) {
            const int nb = (c0 + nt * 16 + kg * 4) * 2;
#pragma unroll
            for (int et = 0; et < 2; ++et) {
                const int e = wq * 32 + et * 16 + m;
                s16x4 pkv;
#pragma unroll
                for (int r = 0; r < 4; ++r) pkv[r] = to_bf16(fmaxf(acc[nt][et][r], 0.0f));
                const int byt = (e * 256 + nb) ^ (m << 4);
                *(s16x4*)((char*)h2s + byt) = pkv;
            }
        }
        __syncthreads();   // B2: h2 ready

        // ---------- layer 3: h3' = W3^T · h2^T + b3 ----------
        f32x4 acc3[2][2];
        {
            f32x4 b3f0 = *(const f32x4*)(b3p + c0 + kg * 4);
            f32x4 b3f1 = *(const f32x4*)(b3p + c0 + 16 + kg * 4);
#pragma unroll
            for (int et = 0; et < 2; ++et) { acc3[0][et] = b3f0; acc3[1][et] = b3f1; }
        }
#pragma unroll
        for (int ks = 0; ks < 4; ++ks) {
#pragma unroll
            for (int et = 0; et < 2; ++et) {
                const int e = wq * 32 + et * 16 + m;
                const int byt = (e * 256 + (ks * 32 + kg * 8) * 2) ^ (m << 4);
                s16x8 hf = *(const s16x8*)((const char*)h2s + byt);
                acc3[0][et] = __builtin_amdgcn_mfma_f32_16x16x32_bf16(wf3[0][ks], hf, acc3[0][et], 0, 0, 0);
                acc3[1][et] = __builtin_amdgcn_mfma_f32_16x16x32_bf16(wf3[1][ks], hf, acc3[1][et], 0, 0, 0);
            }
        }

        // ---------- LayerNorm stats: single pass (sum + sumsq) ----------
        float pS[2], pQ[2];
#pragma unroll
        for (int et = 0; et < 2; ++et) {
            float s0 = 0.0f, s1 = 0.0f;
#pragma unroll
            for (int nt = 0; nt < 2; ++nt)
#pragma unroll
                for (int r = 0; r < 4; ++r) {
                    float x = acc3[nt][et][r];
                    s0 += x;
                    s1 = fmaf(x, x, s1);
                }
            s0 += __shfl_xor(s0, 16);
            s0 += __shfl_xor(s0, 32);
            s1 += __shfl_xor(s1, 16);
            s1 += __shfl_xor(s1, 32);
            pS[et] = s0;
            pQ[et] = s1;
        }
        if (kg < 2) {   // one writer per (et, m): kg0 -> et0, kg1 -> et1
            const float vS = (kg == 0) ? pS[0] : pS[1];
            const float vQ = (kg == 0) ? pQ[0] : pQ[1];
            redS[(wq * 32 + kg * 16 + m) * 4 + cq] = vS;
            redQ[(wq * 32 + kg * 16 + m) * 4 + cq] = vQ;
        }
        __syncthreads();   // B3: stats ready

        // ---------- finish LN + scale/shift + mask + streaming store ----------
        f32x4 gf0  = *(const f32x4*)(gp + c0 + kg * 4);
        f32x4 gf1  = *(const f32x4*)(gp + c0 + 16 + kg * 4);
        f32x4 bbf0 = *(const f32x4*)(bp + c0 + kg * 4);
        f32x4 bbf1 = *(const f32x4*)(bp + c0 + 16 + kg * 4);
#pragma unroll
        for (int et = 0; et < 2; ++et) {
            const int e = wq * 32 + et * 16 + m;
            f32x4 vS = *(const f32x4*)&redS[e * 4];
            f32x4 vQ = *(const f32x4*)&redQ[e * 4];
            const float mu  = (vS[0] + vS[1] + vS[2] + vS[3]) * (1.0f / 128.0f);
            const float ex2 = (vQ[0] + vQ[1] + vQ[2] + vQ[3]) * (1.0f / 128.0f);
            const float inv = rsqrtf(ex2 - mu * mu + 1e-5f);
            f32x4 o;
#pragma unroll
            for (int r = 0; r < 4; ++r)
                o[r] = ((acc3[0][et][r] - mu) * inv * gf0[r] + bbf0[r]) * pmv[et];
            store_stream(out + ((size_t)(i * NRES + j0 + e)) * C_P + c0 + kg * 4, o);
#pragma unroll
            for (int r = 0; r < 4; ++r)
                o[r] = ((acc3[1][et][r] - mu) * inv * gf1[r] + bbf1[r]) * pmv[et];
            store_stream(out + ((size_t)(i * NRES + j0 + e)) * C_P + c0 + 16 + kg * 4, o);
        }
    }
}

// ---------------------------------------------------------------------------
extern "C" void kernel_launch(void* const* d_in, const int* in_sizes, int n_in,
                              void* d_out, int out_size, void* d_ws, size_t ws_size,
                              hipStream_t stream) {
    const float* s    = (const float*)d_in[0];
    const float* tpos = (const float*)d_in[1];
    const float* scp  = (const float*)d_in[2];
    const float* pm   = (const float*)d_in[3];
    const float* dm   = (const float*)d_in[4];
    const float* W_sp = (const float*)d_in[5];
    const float* b_sp = (const float*)d_in[6];
    const float* W_rp = (const float*)d_in[7];
    const float* b_rp = (const float*)d_in[8];
    const float* W1   = (const float*)d_in[9];
    const float* b1   = (const float*)d_in[10];
    const float* W2   = (const float*)d_in[11];
    const float* b2   = (const float*)d_in[12];
    const float* W3   = (const float*)d_in[13];
    const float* b3   = (const float*)d_in[14];
    const float* lng  = (const float*)d_in[15];
    const float* lnb  = (const float*)d_in[16];
    float* out = (float*)d_out;

    float* ws    = (float*)d_ws;
    float* A     = ws;                        // 768*128
    float* Bt    = A + NRES * C_P;            // 768*128
    float* Wcomb = Bt + NRES * C_P;           // 65*128
    float* RP    = Wcomb + (FEAT + 1) * C_P;  // 1535*128
    short* Wt2   = (short*)(RP + (2 * NRES - 1) * C_P);  // 128*128 bf16
    short* Wt3   = Wt2 + C_P * C_P;
    unsigned short* bins = (unsigned short*)(Wt3 + C_P * C_P); // 768*768

    // R12 probe: known-good pure-write stream over the full output buffer.
    // Measured separately by rocprof; edge_kernel then overwrites everything.
    probe_fill_kernel<<<2048, 256, 0, stream>>>(out, (size_t)out_size / 4);

    node_kernel<<<NRES, 128, 0, stream>>>(s, dm, W_sp, b_sp, W1, b1, A, Bt);
    wcomb_kernel<<<FEAT + 1, 128, 0, stream>>>(W_rp, b_rp, W1, Wcomb);
    rp_kernel<<<2 * NRES - 1, 128, 0, stream>>>(Wcomb, RP);
    wt_kernel<<<256, 128, 0, stream>>>(W2, W3, Wt2, Wt3);
    bins_kernel<<<NEDGE / 256, 256, 0, stream>>>(tpos, scp, bins);
    edge_kernel<<<512, 512, 0, stream>>>(A, Bt, RP, W1, Wt2, Wt3, b2, b3,
                                         lng, lnb, bins, pm, out);
}

// Round 13
// 263.851 us; speedup vs baseline: 1.1570x; 1.1570x over previous
//
#include <hip/hip_runtime.h>
#include <hip/hip_bf16.h>

#define NRES   768
#define C_S    256
#define C_P    128
#define FEAT   64
#define NTILES (NRES * (NRES / 64))   // 9216
#define NEDGE  (NRES * NRES)          // 589824

typedef float f32x4 __attribute__((ext_vector_type(4)));
typedef short s16x8 __attribute__((ext_vector_type(8)));
typedef short s16x4 __attribute__((ext_vector_type(4)));

__device__ __forceinline__ short to_bf16(float f) {
    unsigned u = __builtin_bit_cast(unsigned, f);
    u += 0x7fffu + ((u >> 16) & 1u);   // RNE
    return (short)(u >> 16);
}

// Streaming store (kept for fallback kernel)
__device__ __forceinline__ void store_stream(float* p, f32x4 v) {
    asm volatile("global_store_dwordx4 %0, %1, off sc0 sc1 nt"
                 :: "v"(p), "v"(v) : "memory");
}

// ---------------------------------------------------------------------------
__device__ __forceinline__ int bin_idx(float d) {
    const float lo0  = 0.001f;
    const float step = (20.0f - 0.001f) / 21.0f;
    int k = (int)floorf((d - lo0) / step);
    if (k < -1) k = -1;
    if (k > 21) k = 21;
    for (int kk = k + 1; kk >= k - 1; --kk) {
        if (kk < 0 || kk > 21) continue;
        float lk = lo0 + (float)kk * step;
        float uk = (kk < 21) ? (lo0 + (float)(kk + 1) * step) : 1e8f;
        if (d > lk && d < uk) return kk;
    }
    return -1;
}

// ---------------------------------------------------------------------------
__global__ void bins_kernel(const float* __restrict__ tp, const float* __restrict__ sp,
                            unsigned short* __restrict__ bins) {
    const int idx = blockIdx.x * 256 + threadIdx.x;
    if (idx >= NEDGE) return;
    const int i = idx / NRES;
    const int j = idx - i * NRES;
    float dx = tp[i*3+0] - tp[j*3+0];
    float dy = tp[i*3+1] - tp[j*3+1];
    float dz = tp[i*3+2] - tp[j*3+2];
    const int bd = bin_idx(sqrtf(dx*dx + dy*dy + dz*dz));
    dx = sp[i*3+0] - sp[j*3+0];
    dy = sp[i*3+1] - sp[j*3+1];
    dz = sp[i*3+2] - sp[j*3+2];
    const int bs = bin_idx(sqrtf(dx*dx + dy*dy + dz*dz));
    bins[idx] = (unsigned short)((bd + 1) | ((bs + 1) << 8));
}

// ---------------------------------------------------------------------------
__global__ void node_kernel(const float* __restrict__ s, const float* __restrict__ dm,
                            const float* __restrict__ W_sp, const float* __restrict__ b_sp,
                            const float* __restrict__ W1, const float* __restrict__ b1,
                            float* __restrict__ A, float* __restrict__ Bt) {
    __shared__ float srow[C_S];
    __shared__ float psh[FEAT];
    const int i = blockIdx.x;
    const int t = threadIdx.x;  // 128 threads
    srow[t]       = s[i * C_S + t];
    srow[t + 128] = s[i * C_S + 128 + t];
    __syncthreads();
    if (t < FEAT) {
        float acc = b_sp[t];
        for (int m = 0; m < C_S; ++m) acc = fmaf(srow[m], W_sp[m * FEAT + t], acc);
        psh[t] = acc;
    }
    __syncthreads();
    const float d = dm[i];
    float accA = fmaf(d, W1[236 * C_P + t], b1[t]);
    float accB = d * W1[237 * C_P + t];
    for (int k = 0; k < FEAT; ++k) {
        float p = psh[k];
        accA = fmaf(p, W1[k * C_P + t], accA);
        accB = fmaf(p, W1[(FEAT + k) * C_P + t], accB);
    }
    A[i * C_P + t]  = accA;
    Bt[i * C_P + t] = accB;
}

// ---------------------------------------------------------------------------
__global__ void wcomb_kernel(const float* __restrict__ W_rp, const float* __restrict__ b_rp,
                             const float* __restrict__ W1, float* __restrict__ Wcomb) {
    const int k = blockIdx.x;   // 0..64
    const int c = threadIdx.x;  // 128
    float acc = 0.0f;
    if (k < FEAT) {
        for (int m = 0; m < FEAT; ++m)
            acc = fmaf(W_rp[k * FEAT + m], W1[(2 * FEAT + m) * C_P + c], acc);
    } else {
        for (int m = 0; m < FEAT; ++m)
            acc = fmaf(b_rp[m], W1[(2 * FEAT + m) * C_P + c], acc);
    }
    Wcomb[k * C_P + c] = acc;
}

// ---------------------------------------------------------------------------
__global__ void rp_kernel(const float* __restrict__ Wcomb, float* __restrict__ RP) {
    __shared__ float emb[FEAT];
    const int bi = blockIdx.x;            // 0..1534
    const float d = (float)(bi - (NRES - 1));
    const int c = threadIdx.x;            // 128
    if (c < FEAT / 2) {
        float expo = 2.0f * (float)c / (float)FEAT;
        float freq = 3.14159265358979323846f / powf(2056.0f, expo);
        float ang = d * freq;
        emb[c]            = sinf(ang);
        emb[c + FEAT / 2] = cosf(ang);
    }
    __syncthreads();
    float acc = Wcomb[FEAT * C_P + c];
    for (int k = 0; k < FEAT; ++k) acc = fmaf(emb[k], Wcomb[k * C_P + c], acc);
    RP[bi * C_P + c] = acc;
}

// ---------------------------------------------------------------------------
__global__ void wt_kernel(const float* __restrict__ W2, const float* __restrict__ W3,
                          short* __restrict__ Wt2, short* __restrict__ Wt3) {
    const int n = blockIdx.x & 127;
    const int k = threadIdx.x;
    if (blockIdx.x < 128) Wt2[n * C_P + k] = to_bf16(W2[k * C_P + n]);
    else                  Wt3[n * C_P + k] = to_bf16(W3[k * C_P + n]);
}

// ---------------------------------------------------------------------------
// R13 kernel A: h1 builder. Pure streaming: absorbs the bins->W1 dependent
// gather at high TLP and writes h1 PRE-SWIZZLED, tile-contiguous (16KB/tile)
// so the GEMM kernel can global_load_lds it linearly (m173 pattern: swizzle
// lives in the global layout). Thread's store dest is linear; source channel
// c = (brow ^ ((e&15)<<4))>>1 (XOR swizzle is an involution).
__global__ __launch_bounds__(256) void h1_kernel(
    const float* __restrict__ A, const float* __restrict__ Bt,
    const float* __restrict__ RP, const float* __restrict__ W1,
    const unsigned short* __restrict__ bins, short* __restrict__ h1g)
{
    const int b  = blockIdx.x;         // tile id
    const int i  = b / 12;
    const int j0 = (b % 12) * 64;
    const int t  = threadIdx.x;
    short* hg = h1g + (size_t)b * 8192;
#pragma unroll
    for (int it = 0; it < 4; ++it) {
        const int idx  = it * 2048 + t * 8;        // short offset in tile (16B aligned)
        const int e    = idx >> 7;                 // row (128 shorts/row)
        const int brow = (idx & 127) * 2;          // byte offset within row
        const int c    = (brow ^ ((e & 15) << 4)) >> 1;  // source channel (8 contiguous)
        const int j    = j0 + e;
        const unsigned pk = bins[i * NRES + j];
        const int bd = (int)(pk & 0xffu) - 1;
        const int bs = (int)(pk >> 8) - 1;
        const float fd = (bd < 0) ? 0.0f : 1.0f;
        const float fs = (bs < 0) ? 0.0f : 1.0f;
        const float* Ap = A  + i * C_P + c;
        const float* Bp = Bt + j * C_P + c;
        const float* Rp = RP + (i - j + NRES - 1) * C_P + c;
        const float* Wd = W1 + (192 + (bd < 0 ? 0 : bd)) * C_P + c;
        const float* Ws = W1 + (214 + (bs < 0 ? 0 : bs)) * C_P + c;
        s16x8 pkv;
#pragma unroll
        for (int h = 0; h < 2; ++h) {
            f32x4 a  = *(const f32x4*)(Ap + h * 4);
            f32x4 bb = *(const f32x4*)(Bp + h * 4);
            f32x4 r  = *(const f32x4*)(Rp + h * 4);
            f32x4 w  = *(const f32x4*)(Wd + h * 4);
            f32x4 s  = *(const f32x4*)(Ws + h * 4);
#pragma unroll
            for (int u = 0; u < 4; ++u)
                pkv[h * 4 + u] = to_bf16(fmaxf(a[u] + bb[u] + r[u] + fd * w[u] + fs * s[u], 0.0f));
        }
        *(s16x8*)(hg + idx) = pkv;   // linear, fully coalesced
    }
}

// ---------------------------------------------------------------------------
// R13 kernel B: GEMM+LN. One tile/block, 512 thr. Read side = 2 glds + 16
// weight frags (no dependent chains); h1 tile lands in LDS already swizzled.
__global__ __launch_bounds__(512, 4) void gemm_kernel(
    const short* __restrict__ h1g,
    const short* __restrict__ Wt2, const short* __restrict__ Wt3,
    const float* __restrict__ b2, const float* __restrict__ b3,
    const float* __restrict__ lng, const float* __restrict__ lnb,
    const float* __restrict__ pm, float* __restrict__ out)
{
    __shared__ short h1s[64 * C_P];   // 16KB, holds swizzled tile (linear copy)
    __shared__ short h2s[64 * C_P];
    __shared__ float redS[64 * 4];
    __shared__ float redQ[64 * 4];

    const int bidx = blockIdx.x;
    const int i    = bidx / 12;
    const int j0   = (bidx % 12) * 64;
    const int t    = threadIdx.x;
    const int lane = t & 63;
    const int q    = t >> 6;
    const int m    = lane & 15;
    const int kg   = lane >> 4;
    const int wq   = q >> 2;
    const int cq   = q & 3;
    const int c0   = cq * 32;

    // ---- stage h1 tile: wave q copies bytes [q*2K, q*2K+2K), 16B/lane ----
    {
        const char* src = (const char*)(h1g + (size_t)bidx * 8192);
#pragma unroll
        for (int it = 0; it < 2; ++it) {
            const int off = q * 2048 + it * 1024;
            __builtin_amdgcn_global_load_lds(
                (const __attribute__((address_space(1))) unsigned int*)(src + off + lane * 16),
                (__attribute__((address_space(3))) unsigned int*)((char*)h1s + off),
                16, 0, 0);
        }
    }

    // ---- weights + pm issued while staging is in flight ----
    s16x8 wf2[2][4];
#pragma unroll
    for (int nt = 0; nt < 2; ++nt) {
        const int n = c0 + nt * 16 + m;
#pragma unroll
        for (int ks = 0; ks < 4; ++ks)
            wf2[nt][ks] = *(const s16x8*)(Wt2 + n * C_P + ks * 32 + kg * 8);
    }
    float pmv[2];
#pragma unroll
    for (int et = 0; et < 2; ++et) pmv[et] = pm[i * NRES + j0 + wq * 32 + et * 16 + m];

    asm volatile("s_waitcnt vmcnt(0)" ::: "memory");
    __syncthreads();   // B1: h1 staged

    // ---------- layer 2 ----------
    f32x4 acc[2][2];
    {
        f32x4 b2f0 = *(const f32x4*)(b2 + c0 + kg * 4);
        f32x4 b2f1 = *(const f32x4*)(b2 + c0 + 16 + kg * 4);
#pragma unroll
        for (int et = 0; et < 2; ++et) { acc[0][et] = b2f0; acc[1][et] = b2f1; }
    }
#pragma unroll
    for (int ks = 0; ks < 4; ++ks) {
#pragma unroll
        for (int et = 0; et < 2; ++et) {
            const int e = wq * 32 + et * 16 + m;
            const int byt = (e * 256 + (ks * 32 + kg * 8) * 2) ^ (m << 4);
            s16x8 hf = *(const s16x8*)((const char*)h1s + byt);
            acc[0][et] = __builtin_amdgcn_mfma_f32_16x16x32_bf16(wf2[0][ks], hf, acc[0][et], 0, 0, 0);
            acc[1][et] = __builtin_amdgcn_mfma_f32_16x16x32_bf16(wf2[1][ks], hf, acc[1][et], 0, 0, 0);
        }
    }

    // ---- layer-3 weights (wf2 dead) ----
    s16x8 wf3[2][4];
#pragma unroll
    for (int nt = 0; nt < 2; ++nt) {
        const int n = c0 + nt * 16 + m;
#pragma unroll
        for (int ks = 0; ks < 4; ++ks)
            wf3[nt][ks] = *(const s16x8*)(Wt3 + n * C_P + ks * 32 + kg * 8);
    }

#pragma unroll
    for (int nt = 0; nt < 2; ++nt) {
        const int nb = (c0 + nt * 16 + kg * 4) * 2;
#pragma unroll
        for (int et = 0; et < 2; ++et) {
            const int e = wq * 32 + et * 16 + m;
            s16x4 pkv;
#pragma unroll
            for (int r = 0; r < 4; ++r) pkv[r] = to_bf16(fmaxf(acc[nt][et][r], 0.0f));
            const int byt = (e * 256 + nb) ^ (m << 4);
            *(s16x4*)((char*)h2s + byt) = pkv;
        }
    }
    __syncthreads();   // B2: h2 ready

    // ---------- layer 3 ----------
    f32x4 acc3[2][2];
    {
        f32x4 b3f0 = *(const f32x4*)(b3 + c0 + kg * 4);
        f32x4 b3f1 = *(const f32x4*)(b3 + c0 + 16 + kg * 4);
#pragma unroll
        for (int et = 0; et < 2; ++et) { acc3[0][et] = b3f0; acc3[1][et] = b3f1; }
    }
#pragma unroll
    for (int ks = 0; ks < 4; ++ks) {
#pragma unroll
        for (int et = 0; et < 2; ++et) {
            const int e = wq * 32 + et * 16 + m;
            const int byt = (e * 256 + (ks * 32 + kg * 8) * 2) ^ (m << 4);
            s16x8 hf = *(const s16x8*)((const char*)h2s + byt);
            acc3[0][et] = __builtin_amdgcn_mfma_f32_16x16x32_bf16(wf3[0][ks], hf, acc3[0][et], 0, 0, 0);
            acc3[1][et] = __builtin_amdgcn_mfma_f32_16x16x32_bf16(wf3[1][ks], hf, acc3[1][et], 0, 0, 0);
        }
    }

    // ---------- LN stats ----------
    float pS[2], pQ[2];
#pragma unroll
    for (int et = 0; et < 2; ++et) {
        float s0 = 0.0f, s1 = 0.0f;
#pragma unroll
        for (int nt = 0; nt < 2; ++nt)
#pragma unroll
            for (int r = 0; r < 4; ++r) {
                float x = acc3[nt][et][r];
                s0 += x;
                s1 = fmaf(x, x, s1);
            }
        s0 += __shfl_xor(s0, 16);
        s0 += __shfl_xor(s0, 32);
        s1 += __shfl_xor(s1, 16);
        s1 += __shfl_xor(s1, 32);
        pS[et] = s0;
        pQ[et] = s1;
    }
    if (kg < 2) {
        const float vS = (kg == 0) ? pS[0] : pS[1];
        const float vQ = (kg == 0) ? pQ[0] : pQ[1];
        redS[(wq * 32 + kg * 16 + m) * 4 + cq] = vS;
        redQ[(wq * 32 + kg * 16 + m) * 4 + cq] = vQ;
    }
    __syncthreads();   // B3

    // ---------- epilogue ----------
    f32x4 gf0  = *(const f32x4*)(lng + c0 + kg * 4);
    f32x4 gf1  = *(const f32x4*)(lng + c0 + 16 + kg * 4);
    f32x4 bbf0 = *(const f32x4*)(lnb + c0 + kg * 4);
    f32x4 bbf1 = *(const f32x4*)(lnb + c0 + 16 + kg * 4);
#pragma unroll
    for (int et = 0; et < 2; ++et) {
        const int e = wq * 32 + et * 16 + m;
        f32x4 vS = *(const f32x4*)&redS[e * 4];
        f32x4 vQ = *(const f32x4*)&redQ[e * 4];
        const float mu  = (vS[0] + vS[1] + vS[2] + vS[3]) * (1.0f / 128.0f);
        const float ex2 = (vQ[0] + vQ[1] + vQ[2] + vQ[3]) * (1.0f / 128.0f);
        const float inv = rsqrtf(ex2 - mu * mu + 1e-5f);
        f32x4 o;
#pragma unroll
        for (int r = 0; r < 4; ++r)
            o[r] = ((acc3[0][et][r] - mu) * inv * gf0[r] + bbf0[r]) * pmv[et];
        *(f32x4*)(out + ((size_t)(i * NRES + j0 + e)) * C_P + c0 + kg * 4) = o;
#pragma unroll
        for (int r = 0; r < 4; ++r)
            o[r] = ((acc3[1][et][r] - mu) * inv * gf1[r] + bbf1[r]) * pmv[et];
        *(f32x4*)(out + ((size_t)(i * NRES + j0 + e)) * C_P + c0 + 16 + kg * 4) = o;
    }
}

// ---------------------------------------------------------------------------
// Fallback: R11 fused kernel (used only if ws_size can't hold h1g).
__global__ __launch_bounds__(512, 4) void edge_kernel(
    const float* __restrict__ A, const float* __restrict__ Bt,
    const float* __restrict__ RP, const float* __restrict__ W1,
    const short* __restrict__ Wt2, const short* __restrict__ Wt3,
    const float* __restrict__ b2, const float* __restrict__ b3,
    const float* __restrict__ lng, const float* __restrict__ lnb,
    const unsigned short* __restrict__ bins,
    const float* __restrict__ pm, float* __restrict__ out)
{
    __shared__ short h1s[64 * C_P];
    __shared__ short h2s[64 * C_P];
    __shared__ float redS[64 * 4];
    __shared__ float redQ[64 * 4];

    const int t    = threadIdx.x;
    const int lane = t & 63;
    const int q    = t >> 6;
    const int m    = lane & 15;
    const int kg   = lane >> 4;
    const int wq   = q >> 2;
    const int cq   = q & 3;
    const int c0   = cq * 32;
    const int c4   = t & 31;
    const int er   = t >> 5;

    for (int tile = blockIdx.x; tile < NTILES; tile += gridDim.x) {
        const int i  = tile / 12;
        const int j0 = (tile % 12) * 64;
        const short* w2p = Wt2;
        const short* w3p = Wt3;
        const float* b2p = b2;
        const float* b3p = b3;
        const float* gp  = lng;
        const float* bp  = lnb;
        asm volatile("" : "+s"(w2p), "+s"(w3p), "+s"(b2p), "+s"(b3p), "+s"(gp), "+s"(bp));

        s16x8 wf2[2][4];
#pragma unroll
        for (int nt = 0; nt < 2; ++nt) {
            const int n = c0 + nt * 16 + m;
#pragma unroll
            for (int ks = 0; ks < 4; ++ks)
                wf2[nt][ks] = *(const s16x8*)(w2p + n * C_P + ks * 32 + kg * 8);
        }
        float pmv[2];
#pragma unroll
        for (int et = 0; et < 2; ++et) pmv[et] = pm[i * NRES + j0 + wq * 32 + et * 16 + m];

        {
            const f32x4 aCh = *(const f32x4*)(A + i * C_P + c4 * 4);
#pragma unroll
            for (int it = 0; it < 4; ++it) {
                const int e = it * 16 + er;
                const int j = j0 + e;
                const f32x4 b = *(const f32x4*)(Bt + j * C_P + c4 * 4);
                const f32x4 r = *(const f32x4*)(RP + (i - j + NRES - 1) * C_P + c4 * 4);
                const unsigned pk = bins[i * NRES + j];
                const int bd = (int)(pk & 0xffu) - 1;
                const int bs = (int)(pk >> 8) - 1;
                const f32x4 wd  = *(const f32x4*)(W1 + (192 + (bd < 0 ? 0 : bd)) * C_P + c4 * 4);
                const f32x4 wsb = *(const f32x4*)(W1 + (214 + (bs < 0 ? 0 : bs)) * C_P + c4 * 4);
                const float fd = (bd < 0) ? 0.0f : 1.0f;
                const float fs = (bs < 0) ? 0.0f : 1.0f;
                s16x4 pkv;
#pragma unroll
                for (int u = 0; u < 4; ++u)
                    pkv[u] = to_bf16(fmaxf(aCh[u] + b[u] + r[u] + fd * wd[u] + fs * wsb[u], 0.0f));
                const int byt = (e * 256 + c4 * 8) ^ ((e & 15) << 4);
                *(s16x4*)((char*)h1s + byt) = pkv;
            }
        }
        __syncthreads();

        f32x4 acc[2][2];
        {
            f32x4 b2f0 = *(const f32x4*)(b2p + c0 + kg * 4);
            f32x4 b2f1 = *(const f32x4*)(b2p + c0 + 16 + kg * 4);
#pragma unroll
            for (int et = 0; et < 2; ++et) { acc[0][et] = b2f0; acc[1][et] = b2f1; }
        }
#pragma unroll
        for (int ks = 0; ks < 4; ++ks) {
#pragma unroll
            for (int et = 0; et < 2; ++et) {
                const int e = wq * 32 + et * 16 + m;
                const int byt = (e * 256 + (ks * 32 + kg * 8) * 2) ^ (m << 4);
                s16x8 hf = *(const s16x8*)((const char*)h1s + byt);
                acc[0][et] = __builtin_amdgcn_mfma_f32_16x16x32_bf16(wf2[0][ks], hf, acc[0][et], 0, 0, 0);
                acc[1][et] = __builtin_amdgcn_mfma_f32_16x16x32_bf16(wf2[1][ks], hf, acc[1][et], 0, 0, 0);
            }
        }

        s16x8 wf3[2][4];
#pragma unroll
        for (int nt = 0; nt < 2; ++nt) {
            const int n = c0 + nt * 16 + m;
#pragma unroll
            for (int ks = 0; ks < 4; ++ks)
                wf3[nt][ks] = *(const s16x8*)(w3p + n * C_P + ks * 32 + kg * 8);
        }

#pragma unroll
        for (int nt = 0; nt < 2; ++nt) {
            const int nb = (c0 + nt * 16 + kg * 4) * 2;
#pragma unroll
            for (int et = 0; et < 2; ++et) {
                const int e = wq * 32 + et * 16 + m;
                s16x4 pkv;
#pragma unroll
                for (int r = 0; r < 4; ++r) pkv[r] = to_bf16(fmaxf(acc[nt][et][r], 0.0f));
                const int byt = (e * 256 + nb) ^ (m << 4);
                *(s16x4*)((char*)h2s + byt) = pkv;
            }
        }
        __syncthreads();

        f32x4 acc3[2][2];
        {
            f32x4 b3f0 = *(const f32x4*)(b3p + c0 + kg * 4);
            f32x4 b3f1 = *(const f32x4*)(b3p + c0 + 16 + kg * 4);
#pragma unroll
            for (int et = 0; et < 2; ++et) { acc3[0][et] = b3f0; acc3[1][et] = b3f1; }
        }
#pragma unroll
        for (int ks = 0; ks < 4; ++ks) {
#pragma unroll
            for (int et = 0; et < 2; ++et) {
                const int e = wq * 32 + et * 16 + m;
                const int byt = (e * 256 + (ks * 32 + kg * 8) * 2) ^ (m << 4);
                s16x8 hf = *(const s16x8*)((const char*)h2s + byt);
                acc3[0][et] = __builtin_amdgcn_mfma_f32_16x16x32_bf16(wf3[0][ks], hf, acc3[0][et], 0, 0, 0);
                acc3[1][et] = __builtin_amdgcn_mfma_f32_16x16x32_bf16(wf3[1][ks], hf, acc3[1][et], 0, 0, 0);
            }
        }

        float pS[2], pQ[2];
#pragma unroll
        for (int et = 0; et < 2; ++et) {
            float s0 = 0.0f, s1 = 0.0f;
#pragma unroll
            for (int nt = 0; nt < 2; ++nt)
#pragma unroll
                for (int r = 0; r < 4; ++r) {
                    float x = acc3[nt][et][r];
                    s0 += x;
                    s1 = fmaf(x, x, s1);
                }
            s0 += __shfl_xor(s0, 16);
            s0 += __shfl_xor(s0, 32);
            s1 += __shfl_xor(s1, 16);
            s1 += __shfl_xor(s1, 32);
            pS[et] = s0;
            pQ[et] = s1;
        }
        if (kg < 2) {
            const float vS = (kg == 0) ? pS[0] : pS[1];
            const float vQ = (kg == 0) ? pQ[0] : pQ[1];
            redS[(wq * 32 + kg * 16 + m) * 4 + cq] = vS;
            redQ[(wq * 32 + kg * 16 + m) * 4 + cq] = vQ;
        }
        __syncthreads();

        f32x4 gf0  = *(const f32x4*)(gp + c0 + kg * 4);
        f32x4 gf1  = *(const f32x4*)(gp + c0 + 16 + kg * 4);
        f32x4 bbf0 = *(const f32x4*)(bp + c0 + kg * 4);
        f32x4 bbf1 = *(const f32x4*)(bp + c0 + 16 + kg * 4);
#pragma unroll
        for (int et = 0; et < 2; ++et) {
            const int e = wq * 32 + et * 16 + m;
            f32x4 vS = *(const f32x4*)&redS[e * 4];
            f32x4 vQ = *(const f32x4*)&redQ[e * 4];
            const float mu  = (vS[0] + vS[1] + vS[2] + vS[3]) * (1.0f / 128.0f);
            const float ex2 = (vQ[0] + vQ[1] + vQ[2] + vQ[3]) * (1.0f / 128.0f);
            const float inv = rsqrtf(ex2 - mu * mu + 1e-5f);
            f32x4 o;
#pragma unroll
            for (int r = 0; r < 4; ++r)
                o[r] = ((acc3[0][et][r] - mu) * inv * gf0[r] + bbf0[r]) * pmv[et];
            store_stream(out + ((size_t)(i * NRES + j0 + e)) * C_P + c0 + kg * 4, o);
#pragma unroll
            for (int r = 0; r < 4; ++r)
                o[r] = ((acc3[1][et][r] - mu) * inv * gf1[r] + bbf1[r]) * pmv[et];
            store_stream(out + ((size_t)(i * NRES + j0 + e)) * C_P + c0 + 16 + kg * 4, o);
        }
    }
}

// ---------------------------------------------------------------------------
extern "C" void kernel_launch(void* const* d_in, const int* in_sizes, int n_in,
                              void* d_out, int out_size, void* d_ws, size_t ws_size,
                              hipStream_t stream) {
    const float* s    = (const float*)d_in[0];
    const float* tpos = (const float*)d_in[1];
    const float* scp  = (const float*)d_in[2];
    const float* pm   = (const float*)d_in[3];
    const float* dm   = (const float*)d_in[4];
    const float* W_sp = (const float*)d_in[5];
    const float* b_sp = (const float*)d_in[6];
    const float* W_rp = (const float*)d_in[7];
    const float* b_rp = (const float*)d_in[8];
    const float* W1   = (const float*)d_in[9];
    const float* b1   = (const float*)d_in[10];
    const float* W2   = (const float*)d_in[11];
    const float* b2   = (const float*)d_in[12];
    const float* W3   = (const float*)d_in[13];
    const float* b3   = (const float*)d_in[14];
    const float* lng  = (const float*)d_in[15];
    const float* lnb  = (const float*)d_in[16];
    float* out = (float*)d_out;

    float* ws    = (float*)d_ws;
    float* A     = ws;                        // 768*128 f32
    float* Bt    = A + NRES * C_P;            // 768*128 f32
    float* Wcomb = Bt + NRES * C_P;           // 65*128 f32
    float* RP    = Wcomb + (FEAT + 1) * C_P;  // 1535*128 f32
    short* Wt2   = (short*)(RP + (2 * NRES - 1) * C_P);  // 128*128 bf16
    short* Wt3   = Wt2 + C_P * C_P;
    unsigned short* bins = (unsigned short*)(Wt3 + C_P * C_P); // 768*768
    short* h1g   = (short*)(bins + NEDGE);    // 9216*8192 bf16 = 151MB

    const size_t base_bytes = (size_t)((char*)h1g - (char*)d_ws);
    const size_t need = base_bytes + (size_t)NTILES * 8192 * sizeof(short);

    node_kernel<<<NRES, 128, 0, stream>>>(s, dm, W_sp, b_sp, W1, b1, A, Bt);
    wcomb_kernel<<<FEAT + 1, 128, 0, stream>>>(W_rp, b_rp, W1, Wcomb);
    rp_kernel<<<2 * NRES - 1, 128, 0, stream>>>(Wcomb, RP);
    wt_kernel<<<256, 128, 0, stream>>>(W2, W3, Wt2, Wt3);
    bins_kernel<<<NEDGE / 256, 256, 0, stream>>>(tpos, scp, bins);

    if (ws_size >= need) {
        h1_kernel<<<NTILES, 256, 0, stream>>>(A, Bt, RP, W1, bins, h1g);
        gemm_kernel<<<NTILES, 512, 0, stream>>>(h1g, Wt2, Wt3, b2, b3,
                                                lng, lnb, pm, out);
    } else {
        edge_kernel<<<512, 512, 0, stream>>>(A, Bt, RP, W1, Wt2, Wt3, b2, b3,
                                             lng, lnb, bins, pm, out);
    }
}

// Round 14
// 159.463 us; speedup vs baseline: 1.9144x; 1.6546x over previous
//
#include <hip/hip_runtime.h>
#include <hip/hip_bf16.h>

#define NRES   768
#define C_S    256
#define C_P    128
#define FEAT   64
#define NTILES (NRES * (NRES / 64))   // 9216
#define NEDGE  (NRES * NRES)          // 589824
#define NBLK   768                    // persistent blocks; NTILES/NBLK = 12

typedef float f32x4 __attribute__((ext_vector_type(4)));
typedef short s16x8 __attribute__((ext_vector_type(8)));
typedef short s16x4 __attribute__((ext_vector_type(4)));

__device__ __forceinline__ short to_bf16(float f) {
    unsigned u = __builtin_bit_cast(unsigned, f);
    u += 0x7fffu + ((u >> 16) & 1u);   // RNE
    return (short)(u >> 16);
}

// ---------------------------------------------------------------------------
__device__ __forceinline__ int bin_idx(float d) {
    const float lo0  = 0.001f;
    const float step = (20.0f - 0.001f) / 21.0f;
    int k = (int)floorf((d - lo0) / step);
    if (k < -1) k = -1;
    if (k > 21) k = 21;
    for (int kk = k + 1; kk >= k - 1; --kk) {
        if (kk < 0 || kk > 21) continue;
        float lk = lo0 + (float)kk * step;
        float uk = (kk < 21) ? (lo0 + (float)(kk + 1) * step) : 1e8f;
        if (d > lk && d < uk) return kk;
    }
    return -1;
}

// ---------------------------------------------------------------------------
__global__ void bins_kernel(const float* __restrict__ tp, const float* __restrict__ sp,
                            unsigned short* __restrict__ bins) {
    const int idx = blockIdx.x * 256 + threadIdx.x;
    if (idx >= NEDGE) return;
    const int i = idx / NRES;
    const int j = idx - i * NRES;
    float dx = tp[i*3+0] - tp[j*3+0];
    float dy = tp[i*3+1] - tp[j*3+1];
    float dz = tp[i*3+2] - tp[j*3+2];
    const int bd = bin_idx(sqrtf(dx*dx + dy*dy + dz*dz));
    dx = sp[i*3+0] - sp[j*3+0];
    dy = sp[i*3+1] - sp[j*3+1];
    dz = sp[i*3+2] - sp[j*3+2];
    const int bs = bin_idx(sqrtf(dx*dx + dy*dy + dz*dz));
    bins[idx] = (unsigned short)((bd + 1) | ((bs + 1) << 8));
}

// ---------------------------------------------------------------------------
__global__ void node_kernel(const float* __restrict__ s, const float* __restrict__ dm,
                            const float* __restrict__ W_sp, const float* __restrict__ b_sp,
                            const float* __restrict__ W1, const float* __restrict__ b1,
                            float* __restrict__ A, float* __restrict__ Bt) {
    __shared__ float srow[C_S];
    __shared__ float psh[FEAT];
    const int i = blockIdx.x;
    const int t = threadIdx.x;  // 128 threads
    srow[t]       = s[i * C_S + t];
    srow[t + 128] = s[i * C_S + 128 + t];
    __syncthreads();
    if (t < FEAT) {
        float acc = b_sp[t];
        for (int m = 0; m < C_S; ++m) acc = fmaf(srow[m], W_sp[m * FEAT + t], acc);
        psh[t] = acc;
    }
    __syncthreads();
    const float d = dm[i];
    float accA = fmaf(d, W1[236 * C_P + t], b1[t]);
    float accB = d * W1[237 * C_P + t];
    for (int k = 0; k < FEAT; ++k) {
        float p = psh[k];
        accA = fmaf(p, W1[k * C_P + t], accA);
        accB = fmaf(p, W1[(FEAT + k) * C_P + t], accB);
    }
    A[i * C_P + t]  = accA;
    Bt[i * C_P + t] = accB;
}

// ---------------------------------------------------------------------------
__global__ void wcomb_kernel(const float* __restrict__ W_rp, const float* __restrict__ b_rp,
                             const float* __restrict__ W1, float* __restrict__ Wcomb) {
    const int k = blockIdx.x;   // 0..64
    const int c = threadIdx.x;  // 128
    float acc = 0.0f;
    if (k < FEAT) {
        for (int m = 0; m < FEAT; ++m)
            acc = fmaf(W_rp[k * FEAT + m], W1[(2 * FEAT + m) * C_P + c], acc);
    } else {
        for (int m = 0; m < FEAT; ++m)
            acc = fmaf(b_rp[m], W1[(2 * FEAT + m) * C_P + c], acc);
    }
    Wcomb[k * C_P + c] = acc;
}

// ---------------------------------------------------------------------------
__global__ void rp_kernel(const float* __restrict__ Wcomb, float* __restrict__ RP) {
    __shared__ float emb[FEAT];
    const int bi = blockIdx.x;            // 0..1534
    const float d = (float)(bi - (NRES - 1));
    const int c = threadIdx.x;            // 128
    if (c < FEAT / 2) {
        float expo = 2.0f * (float)c / (float)FEAT;
        float freq = 3.14159265358979323846f / powf(2056.0f, expo);
        float ang = d * freq;
        emb[c]            = sinf(ang);
        emb[c + FEAT / 2] = cosf(ang);
    }
    __syncthreads();
    float acc = Wcomb[FEAT * C_P + c];
    for (int k = 0; k < FEAT; ++k) acc = fmaf(emb[k], Wcomb[k * C_P + c], acc);
    RP[bi * C_P + c] = acc;
}

// ---------------------------------------------------------------------------
__global__ void wt_kernel(const float* __restrict__ W2, const float* __restrict__ W3,
                          short* __restrict__ Wt2, short* __restrict__ Wt3) {
    const int n = blockIdx.x & 127;
    const int k = threadIdx.x;
    if (blockIdx.x < 128) Wt2[n * C_P + k] = to_bf16(W2[k * C_P + n]);
    else                  Wt3[n * C_P + k] = to_bf16(W3[k * C_P + n]);
}

// ---------------------------------------------------------------------------
// Phase-1 staging helpers (issue loads early; commit writes late — T14).
__device__ __forceinline__ void p1_issue(
    int i, int j0, int c4, int er,
    const float* __restrict__ A, const float* __restrict__ Bt,
    const float* __restrict__ RP, const float* __restrict__ W1,
    const unsigned short* __restrict__ bins,
    f32x4& aCh, f32x4* bv, f32x4* rv, f32x4* wdv, f32x4* wsv,
    float* fd, float* fs)
{
    aCh = *(const f32x4*)(A + i * C_P + c4 * 4);
#pragma unroll
    for (int it = 0; it < 4; ++it) {
        const int e = it * 16 + er;
        const int j = j0 + e;
        bv[it] = *(const f32x4*)(Bt + j * C_P + c4 * 4);
        rv[it] = *(const f32x4*)(RP + (i - j + NRES - 1) * C_P + c4 * 4);
        const unsigned pk = bins[i * NRES + j];
        const int bd = (int)(pk & 0xffu) - 1;
        const int bs = (int)(pk >> 8) - 1;
        wdv[it] = *(const f32x4*)(W1 + (192 + (bd < 0 ? 0 : bd)) * C_P + c4 * 4);
        wsv[it] = *(const f32x4*)(W1 + (214 + (bs < 0 ? 0 : bs)) * C_P + c4 * 4);
        fd[it] = (bd < 0) ? 0.0f : 1.0f;
        fs[it] = (bs < 0) ? 0.0f : 1.0f;
    }
}

__device__ __forceinline__ void p1_commit(
    short* buf, int c4, int er,
    const f32x4& aCh, const f32x4* bv, const f32x4* rv,
    const f32x4* wdv, const f32x4* wsv, const float* fd, const float* fs)
{
#pragma unroll
    for (int it = 0; it < 4; ++it) {
        const int e = it * 16 + er;
        s16x4 pkv;
#pragma unroll
        for (int u = 0; u < 4; ++u)
            pkv[u] = to_bf16(fmaxf(
                aCh[u] + bv[it][u] + rv[it][u] + fd[it] * wdv[it][u] + fs[it] * wsv[it][u],
                0.0f));
        const int byt = (e * 256 + c4 * 8) ^ ((e & 15) << 4);
        *(s16x4*)((char*)buf + byt) = pkv;
    }
}

// ---------------------------------------------------------------------------
// R14: persistent fused kernel with CROSS-TILE pipelining. 768 blocks x 512
// thr, 12 tiles each, double-buffered h1 (LDS). Next tile's phase-1 loads
// are ISSUED at loop top and COMMITTED after layer-3 — their latency hides
// under both MFMA phases. 2 barriers/tile (B2,B3); end barrier is redundant:
//   next layer-2 reads bufN  <- writes at commit precede B3           [ok]
//   next h2 writes           <- this layer-3 h2 reads precede B3      [ok]
//   next redS writes (f')    <- this epilogue redS reads precede B2'  [ok]
__global__ __launch_bounds__(512, 1) void edge_kernel(
    const float* __restrict__ A, const float* __restrict__ Bt,
    const float* __restrict__ RP, const float* __restrict__ W1,
    const short* __restrict__ Wt2, const short* __restrict__ Wt3,
    const float* __restrict__ b2, const float* __restrict__ b3,
    const float* __restrict__ lng, const float* __restrict__ lnb,
    const unsigned short* __restrict__ bins,
    const float* __restrict__ pm, float* __restrict__ out)
{
    __shared__ short h1a[64 * C_P];
    __shared__ short h1b[64 * C_P];
    __shared__ short h2s[64 * C_P];
    __shared__ float redS[64 * 4];
    __shared__ float redQ[64 * 4];

    const int t    = threadIdx.x;
    const int lane = t & 63;
    const int q    = t >> 6;       // wave 0..7
    const int m    = lane & 15;
    const int kg   = lane >> 4;
    const int wq   = q >> 2;       // edge half
    const int cq   = q & 3;        // channel quarter
    const int c0   = cq * 32;
    const int c4   = t & 31;       // phase-1 chunk
    const int er   = t >> 5;       // phase-1 row 0..15

    // ---- hoisted (loop-invariant) weights & scale vectors ----
    s16x8 wf2[2][4], wf3[2][4];
#pragma unroll
    for (int nt = 0; nt < 2; ++nt) {
        const int n = c0 + nt * 16 + m;
#pragma unroll
        for (int ks = 0; ks < 4; ++ks) {
            wf2[nt][ks] = *(const s16x8*)(Wt2 + n * C_P + ks * 32 + kg * 8);
            wf3[nt][ks] = *(const s16x8*)(Wt3 + n * C_P + ks * 32 + kg * 8);
        }
    }
    const f32x4 b2f0 = *(const f32x4*)(b2 + c0 + kg * 4);
    const f32x4 b2f1 = *(const f32x4*)(b2 + c0 + 16 + kg * 4);
    const f32x4 b3f0 = *(const f32x4*)(b3 + c0 + kg * 4);
    const f32x4 b3f1 = *(const f32x4*)(b3 + c0 + 16 + kg * 4);
    const f32x4 gf0  = *(const f32x4*)(lng + c0 + kg * 4);
    const f32x4 gf1  = *(const f32x4*)(lng + c0 + 16 + kg * 4);
    const f32x4 bbf0 = *(const f32x4*)(lnb + c0 + kg * 4);
    const f32x4 bbf1 = *(const f32x4*)(lnb + c0 + 16 + kg * 4);

    short* cur = h1a;
    short* nxt = h1b;

    // ---- prologue: phase-1 of first tile -> cur ----
    {
        const int tile = blockIdx.x;
        const int i = tile / 12, j0 = (tile % 12) * 64;
        f32x4 aCh, bv[4], rv[4], wdv[4], wsv[4];
        float fd[4], fs[4];
        p1_issue(i, j0, c4, er, A, Bt, RP, W1, bins, aCh, bv, rv, wdv, wsv, fd, fs);
        p1_commit(cur, c4, er, aCh, bv, rv, wdv, wsv, fd, fs);
    }
    __syncthreads();

    for (int k = 0; k < 12; ++k) {
        const int tile = blockIdx.x + k * NBLK;
        const int i = tile / 12, j0 = (tile % 12) * 64;

        float pmv[2];
#pragma unroll
        for (int et = 0; et < 2; ++et)
            pmv[et] = pm[i * NRES + j0 + wq * 32 + et * 16 + m];

        // ---- issue next tile's phase-1 loads (latency hides under MFMA) ----
        f32x4 aN, bN[4], rN[4], wdN[4], wsN[4];
        float fdN[4], fsN[4];
        const bool hasNext = (k < 11);
        if (hasNext) {
            const int ntile = tile + NBLK;
            p1_issue(ntile / 12, (ntile % 12) * 64, c4, er, A, Bt, RP, W1, bins,
                     aN, bN, rN, wdN, wsN, fdN, fsN);
        }

        // ---------- layer 2: MFMA on cur ----------
        f32x4 acc[2][2];
#pragma unroll
        for (int et = 0; et < 2; ++et) { acc[0][et] = b2f0; acc[1][et] = b2f1; }
#pragma unroll
        for (int ks = 0; ks < 4; ++ks) {
#pragma unroll
            for (int et = 0; et < 2; ++et) {
                const int e = wq * 32 + et * 16 + m;
                const int byt = (e * 256 + (ks * 32 + kg * 8) * 2) ^ (m << 4);
                s16x8 hf = *(const s16x8*)((const char*)cur + byt);
                acc[0][et] = __builtin_amdgcn_mfma_f32_16x16x32_bf16(wf2[0][ks], hf, acc[0][et], 0, 0, 0);
                acc[1][et] = __builtin_amdgcn_mfma_f32_16x16x32_bf16(wf2[1][ks], hf, acc[1][et], 0, 0, 0);
            }
        }

        // ---------- h2 bounce ----------
#pragma unroll
        for (int nt = 0; nt < 2; ++nt) {
            const int nb = (c0 + nt * 16 + kg * 4) * 2;
#pragma unroll
            for (int et = 0; et < 2; ++et) {
                const int e = wq * 32 + et * 16 + m;
                s16x4 pkv;
#pragma unroll
                for (int r = 0; r < 4; ++r) pkv[r] = to_bf16(fmaxf(acc[nt][et][r], 0.0f));
                const int byt = (e * 256 + nb) ^ (m << 4);
                *(s16x4*)((char*)h2s + byt) = pkv;
            }
        }
        __syncthreads();   // B2: h2 ready

        // ---------- layer 3 ----------
        f32x4 acc3[2][2];
#pragma unroll
        for (int et = 0; et < 2; ++et) { acc3[0][et] = b3f0; acc3[1][et] = b3f1; }
#pragma unroll
        for (int ks = 0; ks < 4; ++ks) {
#pragma unroll
            for (int et = 0; et < 2; ++et) {
                const int e = wq * 32 + et * 16 + m;
                const int byt = (e * 256 + (ks * 32 + kg * 8) * 2) ^ (m << 4);
                s16x8 hf = *(const s16x8*)((const char*)h2s + byt);
                acc3[0][et] = __builtin_amdgcn_mfma_f32_16x16x32_bf16(wf3[0][ks], hf, acc3[0][et], 0, 0, 0);
                acc3[1][et] = __builtin_amdgcn_mfma_f32_16x16x32_bf16(wf3[1][ks], hf, acc3[1][et], 0, 0, 0);
            }
        }

        // ---- commit next tile's h1 into nxt (loads returned by now) ----
        if (hasNext)
            p1_commit(nxt, c4, er, aN, bN, rN, wdN, wsN, fdN, fsN);

        // ---------- LN stats ----------
        float pS[2], pQ[2];
#pragma unroll
        for (int et = 0; et < 2; ++et) {
            float s0 = 0.0f, s1 = 0.0f;
#pragma unroll
            for (int nt = 0; nt < 2; ++nt)
#pragma unroll
                for (int r = 0; r < 4; ++r) {
                    float x = acc3[nt][et][r];
                    s0 += x;
                    s1 = fmaf(x, x, s1);
                }
            s0 += __shfl_xor(s0, 16);
            s0 += __shfl_xor(s0, 32);
            s1 += __shfl_xor(s1, 16);
            s1 += __shfl_xor(s1, 32);
            pS[et] = s0;
            pQ[et] = s1;
        }
        if (kg < 2) {
            const float vS = (kg == 0) ? pS[0] : pS[1];
            const float vQ = (kg == 0) ? pQ[0] : pQ[1];
            redS[(wq * 32 + kg * 16 + m) * 4 + cq] = vS;
            redQ[(wq * 32 + kg * 16 + m) * 4 + cq] = vQ;
        }
        __syncthreads();   // B3: stats ready (also orders nxt writes)

        // ---------- epilogue ----------
#pragma unroll
        for (int et = 0; et < 2; ++et) {
            const int e = wq * 32 + et * 16 + m;
            f32x4 vS = *(const f32x4*)&redS[e * 4];
            f32x4 vQ = *(const f32x4*)&redQ[e * 4];
            const float mu  = (vS[0] + vS[1] + vS[2] + vS[3]) * (1.0f / 128.0f);
            const float ex2 = (vQ[0] + vQ[1] + vQ[2] + vQ[3]) * (1.0f / 128.0f);
            const float inv = rsqrtf(ex2 - mu * mu + 1e-5f);
            f32x4 o;
#pragma unroll
            for (int r = 0; r < 4; ++r)
                o[r] = ((acc3[0][et][r] - mu) * inv * gf0[r] + bbf0[r]) * pmv[et];
            *(f32x4*)(out + ((size_t)(i * NRES + j0 + e)) * C_P + c0 + kg * 4) = o;
#pragma unroll
            for (int r = 0; r < 4; ++r)
                o[r] = ((acc3[1][et][r] - mu) * inv * gf1[r] + bbf1[r]) * pmv[et];
            *(f32x4*)(out + ((size_t)(i * NRES + j0 + e)) * C_P + c0 + 16 + kg * 4) = o;
        }

        short* tmp = cur; cur = nxt; nxt = tmp;
    }
}

// ---------------------------------------------------------------------------
extern "C" void kernel_launch(void* const* d_in, const int* in_sizes, int n_in,
                              void* d_out, int out_size, void* d_ws, size_t ws_size,
                              hipStream_t stream) {
    const float* s    = (const float*)d_in[0];
    const float* tpos = (const float*)d_in[1];
    const float* scp  = (const float*)d_in[2];
    const float* pm   = (const float*)d_in[3];
    const float* dm   = (const float*)d_in[4];
    const float* W_sp = (const float*)d_in[5];
    const float* b_sp = (const float*)d_in[6];
    const float* W_rp = (const float*)d_in[7];
    const float* b_rp = (const float*)d_in[8];
    const float* W1   = (const float*)d_in[9];
    const float* b1   = (const float*)d_in[10];
    const float* W2   = (const float*)d_in[11];
    const float* b2   = (const float*)d_in[12];
    const float* W3   = (const float*)d_in[13];
    const float* b3   = (const float*)d_in[14];
    const float* lng  = (const float*)d_in[15];
    const float* lnb  = (const float*)d_in[16];
    float* out = (float*)d_out;

    float* ws    = (float*)d_ws;
    float* A     = ws;                        // 768*128 f32
    float* Bt    = A + NRES * C_P;            // 768*128 f32
    float* Wcomb = Bt + NRES * C_P;           // 65*128 f32
    float* RP    = Wcomb + (FEAT + 1) * C_P;  // 1535*128 f32
    short* Wt2   = (short*)(RP + (2 * NRES - 1) * C_P);  // 128*128 bf16
    short* Wt3   = Wt2 + C_P * C_P;
    unsigned short* bins = (unsigned short*)(Wt3 + C_P * C_P); // 768*768

    node_kernel<<<NRES, 128, 0, stream>>>(s, dm, W_sp, b_sp, W1, b1, A, Bt);
    wcomb_kernel<<<FEAT + 1, 128, 0, stream>>>(W_rp, b_rp, W1, Wcomb);
    rp_kernel<<<2 * NRES - 1, 128, 0, stream>>>(Wcomb, RP);
    wt_kernel<<<256, 128, 0, stream>>>(W2, W3, Wt2, Wt3);
    bins_kernel<<<NEDGE / 256, 256, 0, stream>>>(tpos, scp, bins);
    edge_kernel<<<NBLK, 512, 0, stream>>>(A, Bt, RP, W1, Wt2, Wt3, b2, b3,
                                          lng, lnb, bins, pm, out);
}